// Round 1
// baseline (179.184 us; speedup 1.0000x reference)
//
#include <hip/hip_runtime.h>
#include <stdint.h>

#define NB 32
#define NT 2000
#define NH 256
#define NS 63
#define LDSROW 264   // padded bf16 row stride (528 B)

typedef __attribute__((ext_vector_type(8))) short bf16x8;
typedef __attribute__((ext_vector_type(4))) float f32x4;

__device__ inline unsigned short f2bf(float f) {
  union { float f; uint32_t u; } v; v.f = f;
  return (unsigned short)((v.u + 0x7fffu + ((v.u >> 16) & 1u)) >> 16);  // RNE
}
__device__ inline unsigned int pk2(float a, float b) {
  return (unsigned int)f2bf(a) | ((unsigned int)f2bf(b) << 16);
}
__device__ inline bf16x8 pack8(const float* g) {
  union { bf16x8 v; unsigned int u[4]; } c;
  c.u[0] = pk2(g[0], g[1]); c.u[1] = pk2(g[2], g[3]);
  c.u[2] = pk2(g[4], g[5]); c.u[3] = pk2(g[6], g[7]);
  return c.v;
}

// Pre-packed MFMA B-fragment layouts (bf16), built once per launch in d_ws:
//   W1F: [km:16][w:4][tn:4][lane:64][j:8]  -> 16384 slots * 16 B = 256 KiB
//        element = W1[(hk + quad*8 + j)*NH + w*64 + tn*16 + l16],
//        hk = (km>>3)*256 + (km&7)*32, quad = lane>>4, l16 = lane&15
//   W2F: [ks:8][tn:4][lane:64][j:8]        ->  2048 slots * 16 B =  32 KiB
//        element = (n<NS) ? W2[(ks*32 + quad*8 + j)*NS + n] : 0,  n = tn*16+l16
#define NSLOT1 (16 * 4 * 4 * 64)
#define NSLOT2 (8 * 4 * 64)
#define WS_NEEDED ((size_t)(NSLOT1 + NSLOT2) * 16)

__global__ __launch_bounds__(256) void prep_weights(
    const float* __restrict__ W1, const float* __restrict__ W2,
    unsigned short* __restrict__ w1f, unsigned short* __restrict__ w2f) {
  const int tid = blockIdx.x * 256 + threadIdx.x;
  if (tid < NSLOT1) {
    const int lane = tid & 63;
    const int quad = lane >> 4, l16 = lane & 15;
    int r = tid >> 6;
    const int tn = r & 3; r >>= 2;
    const int wv = r & 3; r >>= 2;
    const int km = r;  // 0..15
    const int kb = (km >> 3) * 256 + (km & 7) * 32 + quad * 8;
    const int n = wv * 64 + tn * 16 + l16;
    ushort4 lo, hi;
    lo.x = f2bf(W1[(size_t)(kb + 0) * NH + n]);
    lo.y = f2bf(W1[(size_t)(kb + 1) * NH + n]);
    lo.z = f2bf(W1[(size_t)(kb + 2) * NH + n]);
    lo.w = f2bf(W1[(size_t)(kb + 3) * NH + n]);
    hi.x = f2bf(W1[(size_t)(kb + 4) * NH + n]);
    hi.y = f2bf(W1[(size_t)(kb + 5) * NH + n]);
    hi.z = f2bf(W1[(size_t)(kb + 6) * NH + n]);
    hi.w = f2bf(W1[(size_t)(kb + 7) * NH + n]);
    *(ushort4*)&w1f[(size_t)tid * 8] = lo;
    *(ushort4*)&w1f[(size_t)tid * 8 + 4] = hi;
  } else if (tid < NSLOT1 + NSLOT2) {
    const int t2 = tid - NSLOT1;
    const int lane = t2 & 63;
    const int quad = lane >> 4, l16 = lane & 15;
    const int tn = (t2 >> 6) & 3;
    const int ks = t2 >> 8;  // 0..7
    const int kb = ks * 32 + quad * 8;
    const int n = tn * 16 + l16;
    ushort4 lo = {0, 0, 0, 0}, hi = {0, 0, 0, 0};
    if (n < NS) {
      lo.x = f2bf(W2[(size_t)(kb + 0) * NS + n]);
      lo.y = f2bf(W2[(size_t)(kb + 1) * NS + n]);
      lo.z = f2bf(W2[(size_t)(kb + 2) * NS + n]);
      lo.w = f2bf(W2[(size_t)(kb + 3) * NS + n]);
      hi.x = f2bf(W2[(size_t)(kb + 4) * NS + n]);
      hi.y = f2bf(W2[(size_t)(kb + 5) * NS + n]);
      hi.z = f2bf(W2[(size_t)(kb + 6) * NS + n]);
      hi.w = f2bf(W2[(size_t)(kb + 7) * NS + n]);
    }
    *(ushort4*)&w2f[(size_t)t2 * 8] = lo;
    *(ushort4*)&w2f[(size_t)t2 * 8 + 4] = hi;
  }
}

// ONE kernel, 256 threads (4 waves), 64-row geometry.
// Block (i, b): trans rows base..base+63 (base = 63*i - 1) in LDS via two MFMA
// GEMMs, then softmax for t in [63*i, 63*i+62].
// PACKED=1: B fragments loaded as single coalesced dwordx4 from pre-packed
// bf16 w1f/w2f (d_ws). PACKED=0: legacy on-the-fly gather from f32 W1/W2.
template <bool PACKED>
__global__ __launch_bounds__(256, 3) void fused_kernel(
    const float* __restrict__ E, const float* __restrict__ logits,
    const int* __restrict__ kw,
    const float* __restrict__ W1, const float* __restrict__ W2,
    const unsigned short* __restrict__ w1f, const unsigned short* __restrict__ w2f,
    const float* __restrict__ b1, const float* __restrict__ b2,
    float* __restrict__ out) {
  const int b = blockIdx.y;
  const int a0 = blockIdx.x * 63;   // first align t of this block
  const int base = a0 - 1;          // first trans row computed
  const int tid = threadIdx.x;
  const int w = tid >> 6;
  const int lane = tid & 63;
  const int quad = lane >> 4;
  const int l16 = lane & 15;
  const int n0 = w * 64;

  __shared__ unsigned short lds[65 * LDSROW];  // 34320 B: E-tile -> h -> TR
  __shared__ float LPs[64 * 64];               // 16384 B: logits rows (separate!)
  float* TRf = (float*)lds;                    // [64][68] f32 (17408 B, in h region)

  // Stage E rows base..base+64 (clamped to [0, NT-1]), f32 -> bf16
  const float* Eb = E + (size_t)b * NT * NH;
  for (int i = tid; i < 65 * 64; i += 256) {
    int row = i >> 6, c4 = (i & 63) << 2;
    int tr = base + row;
    tr = (tr < 0) ? 0 : (tr > NT - 1 ? NT - 1 : tr);
    float4 v = *(const float4*)&Eb[(size_t)tr * NH + c4];
    ushort4 o;
    o.x = f2bf(v.x); o.y = f2bf(v.y); o.z = f2bf(v.z); o.w = f2bf(v.w);
    *(ushort4*)&lds[row * LDSROW + c4] = o;
  }
  // Stage logits rows a0..a0+63 early (latency hides under GEMM1).
  const float* lb = logits + (size_t)b * NT * NS;
  for (int i = tid; i < 64 * 64; i += 256) {
    int j = i >> 6, c = i & 63;
    int t = a0 + j; if (t > NT - 1) t = NT - 1;
    int cc = (c < NS) ? c : NS - 1;
    LPs[i] = lb[(size_t)t * NS + cc];
  }
  __syncthreads();

  // GEMM1: h[m][n] = e[base+m+1]@W1_top + e[base+m]@W1_bot  (m = 0..63,
  // wave w owns cols n0..n0+63)
  f32x4 acc[4][4];
  #pragma unroll
  for (int tm = 0; tm < 4; ++tm)
    #pragma unroll
    for (int tn = 0; tn < 4; ++tn) acc[tm][tn] = (f32x4){0.f, 0.f, 0.f, 0.f};

  if constexpr (PACKED) {
    #pragma unroll
    for (int km = 0; km < 16; ++km) {
      const int aoff = (km >> 3) ? 0 : 1;  // top half pairs e[t+1]
      bf16x8 af[4];
      #pragma unroll
      for (int tm = 0; tm < 4; ++tm)
        af[tm] = *(const bf16x8*)&lds[(tm * 16 + l16 + aoff) * LDSROW +
                                      (km & 7) * 32 + quad * 8];
      #pragma unroll
      for (int tn = 0; tn < 4; ++tn) {
        bf16x8 bq = *(const bf16x8*)&w1f[
            (size_t)(((km << 4) + (w << 2) + tn) * 64 + lane) * 8];
        #pragma unroll
        for (int tm = 0; tm < 4; ++tm)
          acc[tm][tn] = __builtin_amdgcn_mfma_f32_16x16x32_bf16(
              af[tm], bq, acc[tm][tn], 0, 0, 0);
      }
    }
  } else {
    const float* w1p = W1 + (size_t)(quad * 8) * NH + n0 + l16;
    #pragma unroll
    for (int km = 0; km < 16; ++km) {
      const int hk = (km >> 3) * 256 + (km & 7) * 32;
      const int aoff = (km >> 3) ? 0 : 1;
      bf16x8 af[4];
      #pragma unroll
      for (int tm = 0; tm < 4; ++tm)
        af[tm] = *(const bf16x8*)&lds[(tm * 16 + l16 + aoff) * LDSROW +
                                      (km & 7) * 32 + quad * 8];
      float g[8], gn[8];
      #pragma unroll
      for (int j = 0; j < 8; ++j) g[j] = w1p[(size_t)(hk + j) * NH];
      #pragma unroll
      for (int tn = 0; tn < 4; ++tn) {
        if (tn < 3) {
          #pragma unroll
          for (int j = 0; j < 8; ++j)
            gn[j] = w1p[(size_t)(hk + j) * NH + (tn + 1) * 16];
        }
        bf16x8 bq = pack8(g);
        #pragma unroll
        for (int tm = 0; tm < 4; ++tm)
          acc[tm][tn] = __builtin_amdgcn_mfma_f32_16x16x32_bf16(
              af[tm], bq, acc[tm][tn], 0, 0, 0);
        if (tn < 3) {
          #pragma unroll
          for (int j = 0; j < 8; ++j) g[j] = gn[j];
        }
      }
    }
  }
  __syncthreads();  // GEMM1 A-reads done

  // h = relu(acc + b1) -> bf16 LDS rows 0..63
  #pragma unroll
  for (int tn = 0; tn < 4; ++tn) {
    float b1v = b1[n0 + tn * 16 + l16];
    #pragma unroll
    for (int tm = 0; tm < 4; ++tm)
      #pragma unroll
      for (int r = 0; r < 4; ++r) {
        float hv = fmaxf(acc[tm][tn][r] + b1v, 0.f);
        lds[(tm * 16 + quad * 4 + r) * LDSROW + n0 + tn * 16 + l16] = f2bf(hv);
      }
  }
  __syncthreads();

  // GEMM2: wave w -> trans rows m0..m0+15
  const int m0 = w * 16;
  f32x4 acc2[4];
  #pragma unroll
  for (int tn = 0; tn < 4; ++tn) acc2[tn] = (f32x4){0.f, 0.f, 0.f, 0.f};

  if constexpr (PACKED) {
    #pragma unroll
    for (int ks = 0; ks < 8; ++ks) {
      bf16x8 af = *(const bf16x8*)&lds[(m0 + l16) * LDSROW + ks * 32 + quad * 8];
      #pragma unroll
      for (int tn = 0; tn < 4; ++tn) {
        bf16x8 bq = *(const bf16x8*)&w2f[(size_t)(((ks << 2) + tn) * 64 + lane) * 8];
        acc2[tn] = __builtin_amdgcn_mfma_f32_16x16x32_bf16(af, bq, acc2[tn], 0, 0, 0);
      }
    }
  } else {
    #pragma unroll
    for (int ks = 0; ks < 8; ++ks) {
      const int k0 = ks * 32;
      bf16x8 af = *(const bf16x8*)&lds[(m0 + l16) * LDSROW + k0 + quad * 8];
      #pragma unroll
      for (int tn = 0; tn < 4; ++tn) {
        const int n = tn * 16 + l16;
        float g[8];
        #pragma unroll
        for (int j = 0; j < 8; ++j)
          g[j] = (n < NS) ? W2[(size_t)(k0 + quad * 8 + j) * NS + n] : 0.f;
        bf16x8 bq = pack8(g);
        acc2[tn] = __builtin_amdgcn_mfma_f32_16x16x32_bf16(af, bq, acc2[tn], 0, 0, 0);
      }
    }
  }
  __syncthreads();  // all h reads done; h region now reused for TR

  // TR[m][s] = trans[base+m][s] (f32); col 63 = 0 (defined, never used)
  #pragma unroll
  for (int tn = 0; tn < 4; ++tn) {
    int s = tn * 16 + l16;
    float b2v = (s < NS) ? b2[s] : 0.f;
    #pragma unroll
    for (int r = 0; r < 4; ++r)
      TRf[(m0 + quad * 4 + r) * 68 + s] = acc2[tn][r] + b2v;
  }
  __syncthreads();

  // Softmax for t = a0 + j, j in [0, 62]  (scores bounded -> max-free softmax)
  for (int rr = 0; rr < 16; ++rr) {
    const int j = m0 + rr;
    const int t = a0 + j;
    if (j == 63 || t > NT - 1) continue;
    float sc;
    if (t == 0) {
      float v = (lane < NS) ? LPs[lane] : -1e30f;
      float m = v;
      #pragma unroll
      for (int o = 32; o > 0; o >>= 1) m = fmaxf(m, __shfl_xor(m, o));
      float ee = (lane < NS) ? __expf(v - m) : 0.f;
      float ss = ee;
      #pragma unroll
      for (int o = 32; o > 0; o >>= 1) ss += __shfl_xor(ss, o);
      const float lse = m + __logf(ss);
      const float f00 = LPs[kw[b * 32]] - lse;
      sc = ((lane == 0) ? f00 : 0.f) + LPs[64 + lane] + TRf[68 + lane];
    } else if (t == NT - 1) {
      sc = LPs[j * 64 + lane] + TRf[j * 68 + lane];
    } else {
      sc = LPs[j * 64 + lane] + LPs[(j + 1) * 64 + lane] +
           TRf[j * 68 + lane] + TRf[(j + 1) * 68 + lane];
    }
    float e = (lane < NS) ? __expf(sc) : 0.f;
    float s = e;
    #pragma unroll
    for (int o = 32; o > 0; o >>= 1) s += __shfl_xor(s, o);
    if (lane < NS) out[((size_t)b * NT + t) * NS + lane] = e / s;
  }
}

extern "C" void kernel_launch(void* const* d_in, const int* in_sizes, int n_in,
                              void* d_out, int out_size, void* d_ws, size_t ws_size,
                              hipStream_t stream) {
  const float* logits = (const float*)d_in[0];
  const float* E      = (const float*)d_in[1];
  const int*   kw     = (const int*)d_in[2];
  const float* W1     = (const float*)d_in[3];
  const float* b1     = (const float*)d_in[4];
  const float* W2     = (const float*)d_in[5];
  const float* b2     = (const float*)d_in[6];
  float* out = (float*)d_out;

  dim3 g(32, NB);  // 32 t-blocks (63 t's each) x 32 batches = 1024 blocks

  if (ws_size >= WS_NEEDED && d_ws != nullptr) {
    unsigned short* w1f = (unsigned short*)d_ws;
    unsigned short* w2f = w1f + (size_t)NSLOT1 * 8;
    prep_weights<<<dim3((NSLOT1 + NSLOT2) / 256), 256, 0, stream>>>(W1, W2, w1f, w2f);
    fused_kernel<true><<<g, 256, 0, stream>>>(E, logits, kw, W1, W2, w1f, w2f,
                                              b1, b2, out);
  } else {
    fused_kernel<false><<<g, 256, 0, stream>>>(E, logits, kw, W1, W2, nullptr,
                                               nullptr, b1, b2, out);
  }
}

// Round 2
// 139.949 us; speedup vs baseline: 1.2804x; 1.2804x over previous
//
#include <hip/hip_runtime.h>
#include <stdint.h>

#define NB 32
#define NT 2000
#define NH 256
#define NS 63
#define LDSROW 264   // padded bf16 row stride (528 B)

typedef __attribute__((ext_vector_type(8))) short bf16x8;
typedef __attribute__((ext_vector_type(4))) float f32x4;

__device__ inline unsigned short f2bf(float f) {
  union { float f; uint32_t u; } v; v.f = f;
  return (unsigned short)((v.u + 0x7fffu + ((v.u >> 16) & 1u)) >> 16);  // RNE
}
__device__ inline unsigned int pk2(float a, float b) {
  return (unsigned int)f2bf(a) | ((unsigned int)f2bf(b) << 16);
}
__device__ inline bf16x8 pack8(const float* g) {
  union { bf16x8 v; unsigned int u[4]; } c;
  c.u[0] = pk2(g[0], g[1]); c.u[1] = pk2(g[2], g[3]);
  c.u[2] = pk2(g[4], g[5]); c.u[3] = pk2(g[6], g[7]);
  return c.v;
}

// Pre-packed MFMA B-fragment layouts (bf16), built once per launch in d_ws:
//   W1F: [km:16][w:4][tn:4][lane:64][j:8]  -> 16384 slots * 16 B = 256 KiB
//   W2F: [ks:8][tn:4][lane:64][j:8]        ->  2048 slots * 16 B =  32 KiB
#define NSLOT1 (16 * 4 * 4 * 64)
#define NSLOT2 (8 * 4 * 64)
#define WS_NEEDED ((size_t)(NSLOT1 + NSLOT2) * 16)

__global__ __launch_bounds__(256) void prep_weights(
    const float* __restrict__ W1, const float* __restrict__ W2,
    unsigned short* __restrict__ w1f, unsigned short* __restrict__ w2f) {
  const int tid = blockIdx.x * 256 + threadIdx.x;
  if (tid < NSLOT1) {
    const int lane = tid & 63;
    const int quad = lane >> 4, l16 = lane & 15;
    int r = tid >> 6;
    const int tn = r & 3; r >>= 2;
    const int wv = r & 3; r >>= 2;
    const int km = r;  // 0..15
    const int kb = (km >> 3) * 256 + (km & 7) * 32 + quad * 8;
    const int n = wv * 64 + tn * 16 + l16;
    ushort4 lo, hi;
    lo.x = f2bf(W1[(size_t)(kb + 0) * NH + n]);
    lo.y = f2bf(W1[(size_t)(kb + 1) * NH + n]);
    lo.z = f2bf(W1[(size_t)(kb + 2) * NH + n]);
    lo.w = f2bf(W1[(size_t)(kb + 3) * NH + n]);
    hi.x = f2bf(W1[(size_t)(kb + 4) * NH + n]);
    hi.y = f2bf(W1[(size_t)(kb + 5) * NH + n]);
    hi.z = f2bf(W1[(size_t)(kb + 6) * NH + n]);
    hi.w = f2bf(W1[(size_t)(kb + 7) * NH + n]);
    *(ushort4*)&w1f[(size_t)tid * 8] = lo;
    *(ushort4*)&w1f[(size_t)tid * 8 + 4] = hi;
  } else if (tid < NSLOT1 + NSLOT2) {
    const int t2 = tid - NSLOT1;
    const int lane = t2 & 63;
    const int quad = lane >> 4, l16 = lane & 15;
    const int tn = (t2 >> 6) & 3;
    const int ks = t2 >> 8;  // 0..7
    const int kb = ks * 32 + quad * 8;
    const int n = tn * 16 + l16;
    ushort4 lo = {0, 0, 0, 0}, hi = {0, 0, 0, 0};
    if (n < NS) {
      lo.x = f2bf(W2[(size_t)(kb + 0) * NS + n]);
      lo.y = f2bf(W2[(size_t)(kb + 1) * NS + n]);
      lo.z = f2bf(W2[(size_t)(kb + 2) * NS + n]);
      lo.w = f2bf(W2[(size_t)(kb + 3) * NS + n]);
      hi.x = f2bf(W2[(size_t)(kb + 4) * NS + n]);
      hi.y = f2bf(W2[(size_t)(kb + 5) * NS + n]);
      hi.z = f2bf(W2[(size_t)(kb + 6) * NS + n]);
      hi.w = f2bf(W2[(size_t)(kb + 7) * NS + n]);
    }
    *(ushort4*)&w2f[(size_t)t2 * 8] = lo;
    *(ushort4*)&w2f[(size_t)t2 * 8 + 4] = hi;
  }
}

// ONE kernel, 256 threads (4 waves), 64-row geometry.
// Round-2 changes: LPs LDS array removed (logits folded into U = LP + TR + b2
// at TR-write time; loaded straight from global into registers, prefetched
// before GEMM2). LDS 51200 -> 34320 B => 4 blocks/CU, and grid 1024 = 256*4
// is one perfect residency wave. GEMM1 B-fragments register-double-buffered.
template <bool PACKED>
__global__ __launch_bounds__(256, 4) void fused_kernel(
    const float* __restrict__ E, const float* __restrict__ logits,
    const int* __restrict__ kw,
    const float* __restrict__ W1, const float* __restrict__ W2,
    const unsigned short* __restrict__ w1f, const unsigned short* __restrict__ w2f,
    const float* __restrict__ b1, const float* __restrict__ b2,
    float* __restrict__ out) {
  const int b = blockIdx.y;
  const int a0 = blockIdx.x * 63;   // first align t of this block
  const int base = a0 - 1;          // first trans row computed
  const int tid = threadIdx.x;
  const int w = tid >> 6;
  const int lane = tid & 63;
  const int quad = lane >> 4;
  const int l16 = lane & 15;
  const int n0 = w * 64;

  __shared__ unsigned short lds[65 * LDSROW];  // 34320 B: E-tile -> h -> U
  float* TRf = (float*)lds;                    // U[64][68] f32 (17408 B)

  const float* Eb = E + (size_t)b * NT * NH;
  const float* lb = logits + (size_t)b * NT * NS;

  // Stage E rows base..base+64 (clamped), f32 -> bf16. Constant trip count:
  // rows 0..63 in 16 unrolled iters (row = it*4 + w, fully coalesced 1KB/wave),
  // row 64 by wave 0.
  #pragma unroll
  for (int it = 0; it < 16; ++it) {
    const int row = it * 4 + w;
    int tr = base + row;
    tr = (tr < 0) ? 0 : (tr > NT - 1 ? NT - 1 : tr);
    float4 v = *(const float4*)&Eb[(size_t)tr * NH + (lane << 2)];
    ushort4 o;
    o.x = f2bf(v.x); o.y = f2bf(v.y); o.z = f2bf(v.z); o.w = f2bf(v.w);
    *(ushort4*)&lds[row * LDSROW + (lane << 2)] = o;
  }
  if (tid < 64) {
    int tr = base + 64; if (tr > NT - 1) tr = NT - 1;
    float4 v = *(const float4*)&Eb[(size_t)tr * NH + (lane << 2)];
    ushort4 o;
    o.x = f2bf(v.x); o.y = f2bf(v.y); o.z = f2bf(v.z); o.w = f2bf(v.w);
    *(ushort4*)&lds[64 * LDSROW + (lane << 2)] = o;
  }
  __syncthreads();

  // GEMM1: h[m][n] = e[base+m+1]@W1_top + e[base+m]@W1_bot  (m = 0..63,
  // wave w owns cols n0..n0+63)
  f32x4 acc[4][4];
  #pragma unroll
  for (int tm = 0; tm < 4; ++tm)
    #pragma unroll
    for (int tn = 0; tn < 4; ++tn) acc[tm][tn] = (f32x4){0.f, 0.f, 0.f, 0.f};

  if constexpr (PACKED) {
    // fragment (km,tn) lives at wbase + ((km<<4)+tn)*512 ushorts
    const unsigned short* wbase = w1f + (size_t)(((w << 2) * 64) + lane) * 8;
#define W1F_AT(KM, TN) \
  (*(const bf16x8*)(wbase + ((size_t)((((KM) << 4) + (TN))) << 9)))
    bf16x8 cb0 = W1F_AT(0, 0), cb1 = W1F_AT(0, 1);
    bf16x8 cb2 = W1F_AT(0, 2), cb3 = W1F_AT(0, 3);
    #pragma unroll
    for (int km = 0; km < 16; ++km) {
      bf16x8 nb0, nb1, nb2, nb3;
      if (km < 15) {  // one-ahead register double buffer (hides L2 latency)
        nb0 = W1F_AT(km + 1, 0); nb1 = W1F_AT(km + 1, 1);
        nb2 = W1F_AT(km + 1, 2); nb3 = W1F_AT(km + 1, 3);
      }
      const int aoff = (km >> 3) ? 0 : 1;  // top half pairs e[t+1]
      bf16x8 af[4];
      #pragma unroll
      for (int tm = 0; tm < 4; ++tm)
        af[tm] = *(const bf16x8*)&lds[(tm * 16 + l16 + aoff) * LDSROW +
                                      (km & 7) * 32 + quad * 8];
      #pragma unroll
      for (int tm = 0; tm < 4; ++tm)
        acc[tm][0] = __builtin_amdgcn_mfma_f32_16x16x32_bf16(af[tm], cb0, acc[tm][0], 0, 0, 0);
      #pragma unroll
      for (int tm = 0; tm < 4; ++tm)
        acc[tm][1] = __builtin_amdgcn_mfma_f32_16x16x32_bf16(af[tm], cb1, acc[tm][1], 0, 0, 0);
      #pragma unroll
      for (int tm = 0; tm < 4; ++tm)
        acc[tm][2] = __builtin_amdgcn_mfma_f32_16x16x32_bf16(af[tm], cb2, acc[tm][2], 0, 0, 0);
      #pragma unroll
      for (int tm = 0; tm < 4; ++tm)
        acc[tm][3] = __builtin_amdgcn_mfma_f32_16x16x32_bf16(af[tm], cb3, acc[tm][3], 0, 0, 0);
      if (km < 15) { cb0 = nb0; cb1 = nb1; cb2 = nb2; cb3 = nb3; }
    }
#undef W1F_AT
  } else {
    const float* w1p = W1 + (size_t)(quad * 8) * NH + n0 + l16;
    #pragma unroll
    for (int km = 0; km < 16; ++km) {
      const int hk = (km >> 3) * 256 + (km & 7) * 32;
      const int aoff = (km >> 3) ? 0 : 1;
      bf16x8 af[4];
      #pragma unroll
      for (int tm = 0; tm < 4; ++tm)
        af[tm] = *(const bf16x8*)&lds[(tm * 16 + l16 + aoff) * LDSROW +
                                      (km & 7) * 32 + quad * 8];
      float g[8], gn[8];
      #pragma unroll
      for (int j = 0; j < 8; ++j) g[j] = w1p[(size_t)(hk + j) * NH];
      #pragma unroll
      for (int tn = 0; tn < 4; ++tn) {
        if (tn < 3) {
          #pragma unroll
          for (int j = 0; j < 8; ++j)
            gn[j] = w1p[(size_t)(hk + j) * NH + (tn + 1) * 16];
        }
        bf16x8 bq = pack8(g);
        #pragma unroll
        for (int tm = 0; tm < 4; ++tm)
          acc[tm][tn] = __builtin_amdgcn_mfma_f32_16x16x32_bf16(
              af[tm], bq, acc[tm][tn], 0, 0, 0);
        if (tn < 3) {
          #pragma unroll
          for (int j = 0; j < 8; ++j) g[j] = gn[j];
        }
      }
    }
  }
  __syncthreads();  // GEMM1 A-reads done

  // h = relu(acc + b1) -> bf16 LDS rows 0..63
  #pragma unroll
  for (int tn = 0; tn < 4; ++tn) {
    float b1v = b1[n0 + tn * 16 + l16];
    #pragma unroll
    for (int tm = 0; tm < 4; ++tm)
      #pragma unroll
      for (int r = 0; r < 4; ++r) {
        float hv = fmaxf(acc[tm][tn][r] + b1v, 0.f);
        lds[(tm * 16 + quad * 4 + r) * LDSROW + n0 + tn * 16 + l16] = f2bf(hv);
      }
  }
  __syncthreads();

  // Prefetch logits values for this wave's U rows into registers (latency
  // hides under GEMM2). lpv[tn*4+r] pairs with acc2[tn][r].
  const int m0 = w * 16;
  float lpv[16];
  #pragma unroll
  for (int tn = 0; tn < 4; ++tn) {
    const int s = tn * 16 + l16;
    const int cc = (s < NS) ? s : NS - 1;
    #pragma unroll
    for (int r = 0; r < 4; ++r) {
      int tt = a0 + m0 + quad * 4 + r;
      if (tt > NT - 1) tt = NT - 1;
      lpv[tn * 4 + r] = lb[(size_t)tt * NS + cc];
    }
  }

  // GEMM2: wave w -> trans rows m0..m0+15
  f32x4 acc2[4];
  #pragma unroll
  for (int tn = 0; tn < 4; ++tn) acc2[tn] = (f32x4){0.f, 0.f, 0.f, 0.f};

  if constexpr (PACKED) {
    const unsigned short* w2base = w2f + (size_t)lane * 8;
    #pragma unroll
    for (int ks = 0; ks < 8; ++ks) {
      bf16x8 af = *(const bf16x8*)&lds[(m0 + l16) * LDSROW + ks * 32 + quad * 8];
      #pragma unroll
      for (int tn = 0; tn < 4; ++tn) {
        bf16x8 bq = *(const bf16x8*)(w2base + ((size_t)((ks << 2) + tn) << 9));
        acc2[tn] = __builtin_amdgcn_mfma_f32_16x16x32_bf16(af, bq, acc2[tn], 0, 0, 0);
      }
    }
  } else {
    #pragma unroll
    for (int ks = 0; ks < 8; ++ks) {
      const int k0 = ks * 32;
      bf16x8 af = *(const bf16x8*)&lds[(m0 + l16) * LDSROW + k0 + quad * 8];
      #pragma unroll
      for (int tn = 0; tn < 4; ++tn) {
        const int n = tn * 16 + l16;
        float g[8];
        #pragma unroll
        for (int j = 0; j < 8; ++j)
          g[j] = (n < NS) ? W2[(size_t)(k0 + quad * 8 + j) * NS + n] : 0.f;
        bf16x8 bq = pack8(g);
        acc2[tn] = __builtin_amdgcn_mfma_f32_16x16x32_bf16(af, bq, acc2[tn], 0, 0, 0);
      }
    }
  }
  __syncthreads();  // all h reads done; h region now reused for U

  // U[m][s] = trans[base+m][s] + b2[s] + logp-raw[a0+m][s]  (f32)
  // (col 63 defined, never used numerically)
  #pragma unroll
  for (int tn = 0; tn < 4; ++tn) {
    const int s = tn * 16 + l16;
    const float b2v = (s < NS) ? b2[s] : 0.f;
    #pragma unroll
    for (int r = 0; r < 4; ++r)
      TRf[(m0 + quad * 4 + r) * 68 + s] = acc2[tn][r] + b2v + lpv[tn * 4 + r];
  }
  __syncthreads();

  // Softmax for t = a0 + j, j in [0, 62]: sc = U[j] + U[j+1] (interior)
  for (int rr = 0; rr < 16; ++rr) {
    const int j = m0 + rr;
    const int t = a0 + j;
    if (j == 63 || t > NT - 1) continue;
    float sc;
    if (t == 0) {
      float v = (lane < NS) ? lb[lane] : -1e30f;  // logits row 0 from global
      float m = v;
      #pragma unroll
      for (int o = 32; o > 0; o >>= 1) m = fmaxf(m, __shfl_xor(m, o));
      float ee = (lane < NS) ? __expf(v - m) : 0.f;
      float ss = ee;
      #pragma unroll
      for (int o = 32; o > 0; o >>= 1) ss += __shfl_xor(ss, o);
      const float lse = m + __logf(ss);
      const float f00 = lb[kw[b * 32]] - lse;
      sc = ((lane == 0) ? f00 : 0.f) + TRf[68 + lane];  // + U[1]
    } else if (t == NT - 1) {
      sc = TRf[j * 68 + lane];                          // U[j]
    } else {
      sc = TRf[j * 68 + lane] + TRf[(j + 1) * 68 + lane];
    }
    float e = (lane < NS) ? __expf(sc) : 0.f;
    float s = e;
    #pragma unroll
    for (int o = 32; o > 0; o >>= 1) s += __shfl_xor(s, o);
    if (lane < NS) out[((size_t)b * NT + t) * NS + lane] = e / s;
  }
}

extern "C" void kernel_launch(void* const* d_in, const int* in_sizes, int n_in,
                              void* d_out, int out_size, void* d_ws, size_t ws_size,
                              hipStream_t stream) {
  const float* logits = (const float*)d_in[0];
  const float* E      = (const float*)d_in[1];
  const int*   kw     = (const int*)d_in[2];
  const float* W1     = (const float*)d_in[3];
  const float* b1     = (const float*)d_in[4];
  const float* W2     = (const float*)d_in[5];
  const float* b2     = (const float*)d_in[6];
  float* out = (float*)d_out;

  dim3 g(32, NB);  // 32 t-blocks (63 t's each) x 32 batches = 1024 blocks

  if (ws_size >= WS_NEEDED && d_ws != nullptr) {
    unsigned short* w1f = (unsigned short*)d_ws;
    unsigned short* w2f = w1f + (size_t)NSLOT1 * 8;
    prep_weights<<<dim3((NSLOT1 + NSLOT2) / 256), 256, 0, stream>>>(W1, W2, w1f, w2f);
    fused_kernel<true><<<g, 256, 0, stream>>>(E, logits, kw, W1, W2, w1f, w2f,
                                              b1, b2, out);
  } else {
    fused_kernel<false><<<g, 256, 0, stream>>>(E, logits, kw, W1, W2, nullptr,
                                               nullptr, b1, b2, out);
  }
}